// Round 7
// baseline (143.958 us; speedup 1.0000x reference)
//
#include <hip/hip_runtime.h>
#include <stdint.h>

#define NE 102400
#define DIM 256
#define NB 512
#define KROW (DIM / 4)   // 64 packed u32 per row

#define BM 256        // batch tile (2 passes over entity table)
#define BN 128        // entity tile
#define DT 128        // f32 dims per stage
#define KT (DT / 4)   // packed u32 rows per stage = 32

#define SQ 384.0f
#define NINV (-1.0f / 384.0f)

#define XQ_BYTES ((size_t)NB * KROW * 4)        // 128 KiB
#define EQ_BYTES ((size_t)NE * KROW * 4)        // 25 MiB

typedef float vf4 __attribute__((ext_vector_type(4)));

static __device__ __forceinline__ uint32_t quant4(float a, float b, float c,
                                                  float d) {
  uint32_t q = 0;
  asm("v_cvt_pk_u8_f32 %0, %1, 0, %0" : "+v"(q) : "v"(fmaf(a, SQ, 128.5f)));
  asm("v_cvt_pk_u8_f32 %0, %1, 1, %0" : "+v"(q) : "v"(fmaf(b, SQ, 128.5f)));
  asm("v_cvt_pk_u8_f32 %0, %1, 2, %0" : "+v"(q) : "v"(fmaf(c, SQ, 128.5f)));
  asm("v_cvt_pk_u8_f32 %0, %1, 3, %0" : "+v"(q) : "v"(fmaf(d, SQ, 128.5f)));
  return q;
}

// xq[b][k] = quantized (ent[h[b]] + rel[r[b]]), u8 zero-point 128, scale 384.
__global__ __launch_bounds__(64) void make_xq_kernel(
    const float* __restrict__ ent, const float* __restrict__ rel,
    const int* __restrict__ h_idx, const int* __restrict__ r_idx,
    uint32_t* __restrict__ xq) {
  const int b = blockIdx.x;
  const int t = threadIdx.x;
  const float4 e = *(const float4*)&ent[(size_t)h_idx[b] * DIM + t * 4];
  const float4 r = *(const float4*)&rel[(size_t)r_idx[b] * DIM + t * 4];
  xq[(size_t)b * KROW + t] = quant4(e.x + r.x, e.y + r.y, e.z + r.z, e.w + r.w);
}

// eq[n][k] = quantized ent[n], 4 rows per 256-thread block.
__global__ __launch_bounds__(256) void quant_ent_kernel(
    const float* __restrict__ ent, uint32_t* __restrict__ eq) {
  const int n = blockIdx.x * 4 + (threadIdx.x >> 6);
  const int t = threadIdx.x & 63;
  const float4 v = *(const float4*)&ent[(size_t)n * DIM + t * 4];
  eq[(size_t)n * KROW + t] = quant4(v.x, v.y, v.z, v.w);
}

// out[b][n] = -sum_d |x[b][d] - ent[n][d]| via u8 SAD, pre-quantized operands.
// 256x128 tile / 256 threads; 16x8 acc per thread (6 LDS b128 reads per k
// for 128 SADs). tx: 2x4 entity cols (stride-64), ty+s: 4x4 batch rows
// (stride-64 groups).
__global__ __launch_bounds__(256, 2) void transe_sad_q_kernel(
    const uint32_t* __restrict__ eq, const uint32_t* __restrict__ xq,
    float* __restrict__ out) {
  __shared__ uint32_t xT[KT][BM];  // xT[k][b]   32 KiB
  __shared__ uint32_t eT[KT][BN];  // eT[k][n]   16 KiB

  const int n0 = blockIdx.x * BN;
  const int b0 = blockIdx.y * BM;
  const int tid = threadIdx.x;
  const int tx = tid & 15;
  const int ty = tid >> 4;      // 16 values, 4 batch rows each (x4 groups)
  const int s_row = tid >> 1;   // eT staging: 2 threads per row
  const int s_half = tid & 1;

  uint32_t acc[16][8];
#pragma unroll
  for (int i = 0; i < 16; ++i)
#pragma unroll
    for (int j = 0; j < 8; ++j) acc[i][j] = 0u;

  for (int d0 = 0; d0 < DIM; d0 += DT) {
    // ---- stage x tile: 1 thread per row, 8x uint4 = 32 dwords ----
    {
      const uint4* src = (const uint4*)&xq[(size_t)(b0 + tid) * KROW + d0 / 4];
#pragma unroll
      for (int q = 0; q < 8; ++q) {
        uint4 v = src[q];
        xT[q * 4 + 0][tid] = v.x;
        xT[q * 4 + 1][tid] = v.y;
        xT[q * 4 + 2][tid] = v.z;
        xT[q * 4 + 3][tid] = v.w;
      }
    }
    // ---- stage entity tile: 2 threads per row, 4x uint4 ----
    {
      const uint4* src =
          (const uint4*)&eq[(size_t)(n0 + s_row) * KROW + d0 / 4 + s_half * 16];
#pragma unroll
      for (int q = 0; q < 4; ++q) {
        uint4 v = src[q];
        const int k = s_half * 16 + q * 4;
        eT[k + 0][s_row] = v.x;
        eT[k + 1][s_row] = v.y;
        eT[k + 2][s_row] = v.z;
        eT[k + 3][s_row] = v.w;
      }
    }
    __syncthreads();

#pragma unroll 2
    for (int k = 0; k < KT; ++k) {
      uint32_t xw[16], ew[8];
      *(uint4*)&xw[0]  = *(const uint4*)&xT[k][ty * 4];
      *(uint4*)&xw[4]  = *(const uint4*)&xT[k][64 + ty * 4];
      *(uint4*)&xw[8]  = *(const uint4*)&xT[k][128 + ty * 4];
      *(uint4*)&xw[12] = *(const uint4*)&xT[k][192 + ty * 4];
      *(uint4*)&ew[0]  = *(const uint4*)&eT[k][tx * 4];
      *(uint4*)&ew[4]  = *(const uint4*)&eT[k][64 + tx * 4];
#pragma unroll
      for (int i = 0; i < 16; ++i)
#pragma unroll
        for (int j = 0; j < 8; ++j)
          asm("v_sad_u8 %0, %1, %2, %0"
              : "+v"(acc[i][j])
              : "v"(xw[i]), "v"(ew[j]));
    }
    __syncthreads();
  }

  // ---- epilogue: out = -acc/384, non-temporal stores ----
#pragma unroll
  for (int i = 0; i < 16; ++i) {
    const int b = b0 + (i >> 2) * 64 + ty * 4 + (i & 3);
    float* dst = &out[(size_t)b * NE + n0];
    vf4 o0, o1;
    o0.x = (float)acc[i][0] * NINV;
    o0.y = (float)acc[i][1] * NINV;
    o0.z = (float)acc[i][2] * NINV;
    o0.w = (float)acc[i][3] * NINV;
    o1.x = (float)acc[i][4] * NINV;
    o1.y = (float)acc[i][5] * NINV;
    o1.z = (float)acc[i][6] * NINV;
    o1.w = (float)acc[i][7] * NINV;
    __builtin_nontemporal_store(o0, (vf4*)&dst[tx * 4]);
    __builtin_nontemporal_store(o1, (vf4*)&dst[64 + tx * 4]);
  }
}

// ---- fallback (ws too small for eq): R4-style in-kernel quantize ----
__global__ __launch_bounds__(256) void transe_sad_f32_kernel(
    const float* __restrict__ ent, const uint32_t* __restrict__ xq,
    float* __restrict__ out) {
  __shared__ uint32_t xT[KT][128];
  __shared__ uint32_t eT[KT][BN];

  const int n0 = blockIdx.x * BN;
  const int b0 = blockIdx.y * 128;
  const int tid = threadIdx.x;
  const int tx = tid & 15;
  const int ty = tid >> 4;
  const int s_row = tid >> 1;
  const int s_half = tid & 1;

  uint32_t acc[8][8];
#pragma unroll
  for (int i = 0; i < 8; ++i)
#pragma unroll
    for (int j = 0; j < 8; ++j) acc[i][j] = 0u;

  for (int d0 = 0; d0 < DIM; d0 += DT) {
    {
      const uint4* src =
          (const uint4*)&xq[(size_t)(b0 + s_row) * KROW + d0 / 4 + s_half * 16];
#pragma unroll
      for (int q = 0; q < 4; ++q) {
        uint4 v = src[q];
        const int k = s_half * 16 + q * 4;
        xT[k + 0][s_row] = v.x;
        xT[k + 1][s_row] = v.y;
        xT[k + 2][s_row] = v.z;
        xT[k + 3][s_row] = v.w;
      }
    }
    {
      const float4* src =
          (const float4*)&ent[(size_t)(n0 + s_row) * DIM + d0 + s_half * 64];
#pragma unroll
      for (int q = 0; q < 16; ++q) {
        float4 v = src[q];
        eT[s_half * 16 + q][s_row] = quant4(v.x, v.y, v.z, v.w);
      }
    }
    __syncthreads();

#pragma unroll 2
    for (int k = 0; k < KT; ++k) {
      uint32_t xw[8], ew[8];
      *(uint4*)&xw[0] = *(const uint4*)&xT[k][ty * 4];
      *(uint4*)&xw[4] = *(const uint4*)&xT[k][64 + ty * 4];
      *(uint4*)&ew[0] = *(const uint4*)&eT[k][tx * 4];
      *(uint4*)&ew[4] = *(const uint4*)&eT[k][64 + tx * 4];
#pragma unroll
      for (int i = 0; i < 8; ++i)
#pragma unroll
        for (int j = 0; j < 8; ++j)
          asm("v_sad_u8 %0, %1, %2, %0"
              : "+v"(acc[i][j])
              : "v"(xw[i]), "v"(ew[j]));
    }
    __syncthreads();
  }

#pragma unroll
  for (int i = 0; i < 8; ++i) {
    const int b = b0 + ((i & 4) << 4) + ty * 4 + (i & 3);
    float* dst = &out[(size_t)b * NE + n0];
    vf4 o0, o1;
    o0.x = (float)acc[i][0] * NINV;
    o0.y = (float)acc[i][1] * NINV;
    o0.z = (float)acc[i][2] * NINV;
    o0.w = (float)acc[i][3] * NINV;
    o1.x = (float)acc[i][4] * NINV;
    o1.y = (float)acc[i][5] * NINV;
    o1.z = (float)acc[i][6] * NINV;
    o1.w = (float)acc[i][7] * NINV;
    __builtin_nontemporal_store(o0, (vf4*)&dst[tx * 4]);
    __builtin_nontemporal_store(o1, (vf4*)&dst[64 + tx * 4]);
  }
}

extern "C" void kernel_launch(void* const* d_in, const int* in_sizes, int n_in,
                              void* d_out, int out_size, void* d_ws,
                              size_t ws_size, hipStream_t stream) {
  const float* ent = (const float*)d_in[0];
  const float* rel = (const float*)d_in[1];
  const int* h_idx = (const int*)d_in[2];
  const int* r_idx = (const int*)d_in[3];
  float* out = (float*)d_out;

  uint32_t* xq = (uint32_t*)d_ws;
  uint32_t* eq = (uint32_t*)((char*)d_ws + XQ_BYTES);

  make_xq_kernel<<<NB, 64, 0, stream>>>(ent, rel, h_idx, r_idx, xq);

  if (ws_size >= XQ_BYTES + EQ_BYTES) {
    quant_ent_kernel<<<NE / 4, 256, 0, stream>>>(ent, eq);
    dim3 grid(NE / BN, NB / BM);
    transe_sad_q_kernel<<<grid, 256, 0, stream>>>(eq, xq, out);
  } else {
    dim3 grid(NE / BN, NB / 128);
    transe_sad_f32_kernel<<<grid, 256, 0, stream>>>(ent, xq, out);
  }
}